// Round 1
// baseline (9798.272 us; speedup 1.0000x reference)
//
#include <hip/hip_runtime.h>
#include <hip/hip_bf16.h>
#include <cmath>

// PTB LSTM LM forward: embed -> 2x LSTM(1024) -> dense(32000)
// B=32 T=128 EMB=HID=1024 G=4*HID=4096 V=32000
// Baseline: fp32 everywhere (no MFMA yet) to establish correctness + counters.

#define B_   32
#define T_   128
#define BT_  4096      // B*T
#define H_   1024
#define G_   4096      // 4*H
#define V_   32000

// ---------------------------------------------------------------- embed ----
__global__ __launch_bounds__(256) void embed_gather(
    const int* __restrict__ idx, const float* __restrict__ emb,
    float* __restrict__ out)
{
  int row = blockIdx.x;                       // 0..4095
  int r = idx[row];
  const float4* src = (const float4*)(emb + (size_t)r * H_);
  float4* dst = (float4*)(out + (size_t)row * H_);
  dst[threadIdx.x] = src[threadIdx.x];        // 256 x 16B = 4KB row
}

// ----------------------------------------------------------- fp32 GEMM -----
// C[M,N] = A[M,K] @ B[K,N] + bias[N].  M%128==0, N%128==0, K%8==0 (true here).
#define BM 128
#define BN 128
#define BK 8

__global__ __launch_bounds__(256) void sgemm_bias(
    const float* __restrict__ A, const float* __restrict__ Bm,
    const float* __restrict__ bias, float* __restrict__ C,
    int M, int N, int K)
{
  __shared__ float As[BK][BM];
  __shared__ float Bs[BK][BN];
  const int tid = threadIdx.x;
  const int bm = blockIdx.y, bn = blockIdx.x;
  const int tx = tid & 15;        // n-octet
  const int ty = tid >> 4;        // m-octet
  float acc[8][8];
  #pragma unroll
  for (int i = 0; i < 8; ++i)
    #pragma unroll
    for (int j = 0; j < 8; ++j) acc[i][j] = 0.f;

  const float* Ab = A + (size_t)bm * BM * K;
  const float* Bb = Bm + (size_t)bn * BN;
  const int arow = tid >> 1;            // 0..127
  const int acol = (tid & 1) * 4;       // 0 / 4
  const int brow = tid >> 5;            // 0..7
  const int bcol = (tid & 31) * 4;      // 0..124

  for (int k0 = 0; k0 < K; k0 += BK) {
    float4 av = *(const float4*)(Ab + (size_t)arow * K + k0 + acol);
    float4 bv = *(const float4*)(Bb + (size_t)(k0 + brow) * N + bcol);
    __syncthreads();
    As[acol + 0][arow] = av.x;
    As[acol + 1][arow] = av.y;
    As[acol + 2][arow] = av.z;
    As[acol + 3][arow] = av.w;
    *(float4*)&Bs[brow][bcol] = bv;
    __syncthreads();
    #pragma unroll
    for (int k = 0; k < BK; ++k) {
      float a[8], b[8];
      *(float4*)(a)     = *(const float4*)&As[k][ty * 8];
      *(float4*)(a + 4) = *(const float4*)&As[k][ty * 8 + 4];
      *(float4*)(b)     = *(const float4*)&Bs[k][tx * 8];
      *(float4*)(b + 4) = *(const float4*)&Bs[k][tx * 8 + 4];
      #pragma unroll
      for (int i = 0; i < 8; ++i)
        #pragma unroll
        for (int j = 0; j < 8; ++j) acc[i][j] += a[i] * b[j];
    }
  }

  const int crow0 = bm * BM + ty * 8;
  const int ccol0 = bn * BN + tx * 8;
  float bv[8];
  *(float4*)(bv)     = *(const float4*)(bias + ccol0);
  *(float4*)(bv + 4) = *(const float4*)(bias + ccol0 + 4);
  #pragma unroll
  for (int i = 0; i < 8; ++i) {
    size_t r = (size_t)(crow0 + i) * N + ccol0;
    float4 o0 = make_float4(acc[i][0] + bv[0], acc[i][1] + bv[1],
                            acc[i][2] + bv[2], acc[i][3] + bv[3]);
    float4 o1 = make_float4(acc[i][4] + bv[4], acc[i][5] + bv[5],
                            acc[i][6] + bv[6], acc[i][7] + bv[7]);
    *(float4*)(C + r)     = o0;
    *(float4*)(C + r + 4) = o1;
  }
}

// ----------------------------------------------------------- LSTM step -----
// One timestep, one layer, fused z = xz[t] + h_{t-1} @ Wh -> gates -> h,c.
// block = 256 threads = 4 waves; wave w handles gate w, lanes = 64 n values.
// grid = (16 n-blocks, 32 batch)
__device__ __forceinline__ float sigmoidf_(float x) {
  return 1.f / (1.f + __expf(-x));
}

__global__ __launch_bounds__(256) void lstm_step(
    const float* __restrict__ xz,   // [BT, G]
    const float* __restrict__ Wh,   // [H, G]
    float* __restrict__ hs,         // [BT, H] layer output (also h_{t-1} src)
    const float* __restrict__ c_in, // [B, H]
    float* __restrict__ c_out,      // [B, H]
    int t, int first)
{
  const int b = blockIdx.y;
  const int gate = threadIdx.x >> 6;
  const int nl = threadIdx.x & 63;
  const int n = blockIdx.x * 64 + nl;
  const int col = gate * H_ + n;

  __shared__ float hsh[H_];
  __shared__ float zsh[4][64];

  float z;
  if (first) {
    z = xz[(size_t)(b * T_ + t) * G_ + col];
  } else {
    const float* hp = hs + (size_t)(b * T_ + (t - 1)) * H_;
    ((float4*)hsh)[threadIdx.x] = ((const float4*)hp)[threadIdx.x];
    __syncthreads();
    float a0 = 0.f, a1 = 0.f, a2 = 0.f, a3 = 0.f;
    const float* w = Wh + col;
    const float4* h4 = (const float4*)hsh;
    #pragma unroll 8
    for (int kk = 0; kk < H_ / 4; ++kk) {
      float4 hv = h4[kk];
      const float* wk = w + (size_t)kk * 4 * G_;
      a0 += hv.x * wk[0];
      a1 += hv.y * wk[G_];
      a2 += hv.z * wk[2 * G_];
      a3 += hv.w * wk[3 * G_];
    }
    z = xz[(size_t)(b * T_ + t) * G_ + col] + ((a0 + a1) + (a2 + a3));
  }
  zsh[gate][nl] = z;
  __syncthreads();

  if (threadIdx.x < 64) {
    const int nn = blockIdx.x * 64 + threadIdx.x;
    float zi = zsh[0][threadIdx.x];
    float zf = zsh[1][threadIdx.x];
    float zg = zsh[2][threadIdx.x];
    float zo = zsh[3][threadIdx.x];
    float ig = sigmoidf_(zi);
    float fg = sigmoidf_(zf);
    float gg = tanhf(zg);
    float og = sigmoidf_(zo);
    float c = first ? (ig * gg) : fmaf(fg, c_in[b * H_ + nn], ig * gg);
    float h = og * tanhf(c);
    c_out[b * H_ + nn] = c;
    hs[(size_t)(b * T_ + t) * H_ + nn] = h;
  }
}

// -------------------------------------------------------------- launch -----
extern "C" void kernel_launch(void* const* d_in, const int* in_sizes, int n_in,
                              void* d_out, int out_size, void* d_ws, size_t ws_size,
                              hipStream_t stream) {
  const int*   input_seq = (const int*)d_in[0];    // [32,128]
  const float* embedding = (const float*)d_in[1];  // [32000,1024]
  const float* Wx        = (const float*)d_in[2];  // [2,1024,4096]
  const float* Wh        = (const float*)d_in[3];  // [2,1024,4096]
  const float* bvec      = (const float*)d_in[4];  // [2,4096]
  const float* dense_w   = (const float*)d_in[5];  // [1024,32000]
  const float* dense_b   = (const float*)d_in[6];  // [32000]
  float* out = (float*)d_out;                      // [4096,32000]

  // workspace layout (~96.3 MB): y0 | hs1 | xz | c ping-pong
  char* ws = (char*)d_ws;
  float* y0  = (float*)ws;                          // 16 MB  (layer1 in, layer2 out)
  float* hs1 = (float*)(ws + (16u << 20));          // 16 MB  (layer1 out / layer2 in)
  float* xz  = (float*)(ws + (32u << 20));          // 64 MB
  float* cb0 = (float*)(ws + (96u << 20));          // 128 KB
  float* cb1 = cb0 + B_ * H_;                       // 128 KB

  const size_t LW = (size_t)H_ * G_;  // per-layer weight stride

  // 1) embedding gather
  embed_gather<<<BT_, 256, 0, stream>>>(input_seq, embedding, y0);

  // 2) layer 0: xz = y0 @ Wx0 + b0 ; recur
  sgemm_bias<<<dim3(G_ / BN, BT_ / BM), 256, 0, stream>>>(
      y0, Wx, bvec, xz, BT_, G_, H_);
  for (int t = 0; t < T_; ++t) {
    float* cin  = (t & 1) ? cb1 : cb0;
    float* cout = (t & 1) ? cb0 : cb1;
    lstm_step<<<dim3(16, B_), 256, 0, stream>>>(xz, Wh, hs1, cin, cout, t, t == 0);
  }

  // 3) layer 1: xz = hs1 @ Wx1 + b1 ; recur (output into y0)
  sgemm_bias<<<dim3(G_ / BN, BT_ / BM), 256, 0, stream>>>(
      hs1, Wx + LW, bvec + G_, xz, BT_, G_, H_);
  for (int t = 0; t < T_; ++t) {
    float* cin  = (t & 1) ? cb1 : cb0;
    float* cout = (t & 1) ? cb0 : cb1;
    lstm_step<<<dim3(16, B_), 256, 0, stream>>>(xz, Wh + LW, y0, cin, cout, t, t == 0);
  }

  // 4) dense: out = y0 @ dense_w + dense_b
  sgemm_bias<<<dim3(V_ / BN, BT_ / BM), 256, 0, stream>>>(
      y0, dense_w, dense_b, out, BT_, V_, H_);
}